// Round 18
// baseline (270.760 us; speedup 1.0000x reference)
//
#include <hip/hip_runtime.h>
#include <hip/hip_bf16.h>
#include <math.h>

#define Bn 128
#define Tn 512
#define Cn 256
#define Hn 64
#define SCL 0.18033688011112042f   // log2(e)/8 : exp2-domain softmax scale

typedef __attribute__((ext_vector_type(8))) short short8v;   // 8 bf16
typedef __attribute__((ext_vector_type(4))) float float4v;   // MFMA C/D

__device__ __forceinline__ ushort f2bf(float f) {
    __hip_bfloat16 h = __float2bfloat16(f);   // RNE
    return *reinterpret_cast<ushort*>(&h);
}

// ---------------------------------------------------------------------------
// Prep: wcT[col][k] = W_m[k][h] bf16, plain row-major. col: 0-63 q, 64-127 k,
// 128-191 v. Fragments are read from L2 directly (no LDS staging of W).
// ---------------------------------------------------------------------------
__global__ __launch_bounds__(256) void prep_w_kernel(
    const float* __restrict__ Wq, const float* __restrict__ Wk,
    const float* __restrict__ Wv, ushort* __restrict__ wcT)
{
    const int col = blockIdx.x;          // 0..191
    const int kk  = threadIdx.x;         // 0..255
    const float* W = (col < 64) ? Wq : (col < 128) ? Wk : Wv;
    const int h = col & 63;
    wcT[col * Cn + kk] = f2bf(W[kk * Hn + h]);
}

// ---------------------------------------------------------------------------
// Fused QKV + causal flash attention, streaming-chunk form.
// Grid (4, 128): block (c, b) owns q rows [c*128, c*128+128) of batch b.
// 256 thr / 4 waves; wave wv owns q rows [wv*32, wv*32+32) (2 strips of 16).
// Prologue: 2 chunks project Q (verified r6 bounce->A-frag pattern).
// Main loop over 2(c+1) key chunks of 64: stage x chunk -> project K[64t][64h]
// + Vt[64h][64t] into LDS (4 waves cooperate, zero duplication in-block) ->
// flash-attn update per strip. W frags from L2 (96 KB, XCD-resident; no VGPR
// cap). LDS 56 KB -> 2 blocks/CU; imbalance washes out over 512 blocks.
// No q/k/v HBM round-trip at all.
// ---------------------------------------------------------------------------
__global__ __launch_bounds__(256) void fused_attn_kernel(
    const float* __restrict__ x, const ushort* __restrict__ wcT,
    float* __restrict__ out)
{
    __shared__ char lds[57344];
    // xs  @ 0     : 64 rows x 512 B (bf16 x-chunk), row-XOR-swizzled
    // Ks  @ 32768 : 64 t x 128 B  [t][h], swz
    // Vt  @ 40960 : 64 h x 128 B  [h][t], swz
    // bnc @ 49152 : 4 waves x 2 KB
    const int KOFF = 32768, VOFF = 40960, POFF = 49152;

    const int tid  = threadIdx.x;
    const int lane = tid & 63;
    const int wv   = tid >> 6;             // 0..3
    const int lr   = lane & 15;
    const int hi   = lane >> 4;
    const int c    = blockIdx.x;           // q quarter 0..3
    const int b    = blockIdx.y;           // batch
    const long xbase = (long)b * Tn * Cn;
    const long obase = (long)b * Tn * Hn;
    const int qb   = c * 128;
    const int NKT  = 2 * (c + 1);          // key chunks
    const int NC   = 2 + NKT;              // total chunks (2 q + keys)

    char* bnc = lds + POFF + wv * 2048;
    const int bswz = (lr & 7) << 4;

    short8v qa[2][2];                      // [strip][ks] q A-frags
    float4v o[2][4];
    float m[2][4], l[2][4];
    #pragma unroll
    for (int st = 0; st < 2; ++st) {
        #pragma unroll
        for (int n = 0; n < 4; ++n) o[st][n] = (float4v){0.f, 0.f, 0.f, 0.f};
        #pragma unroll
        for (int r = 0; r < 4; ++r) { m[st][r] = -INFINITY; l[st][r] = 0.f; }
    }

    const float4* x4 = (const float4*)(x + xbase);
    // chunk i rows: i<2 -> qb + i*64 ; else (i-2)*64
    float4 xr[16];
#define LOADX(R0) do {                                                        \
    _Pragma("unroll")                                                         \
    for (int i_ = 0; i_ < 16; ++i_) {                                         \
        int idx = tid + i_ * 256;          /* 0..4095 */                      \
        int r_ = idx >> 6, f_ = idx & 63;                                     \
        xr[i_] = x4[((R0) + r_) * 64 + f_];                                   \
    } } while (0)
#define STOREX() do {                                                         \
    _Pragma("unroll")                                                         \
    for (int i_ = 0; i_ < 16; ++i_) {                                         \
        int idx = tid + i_ * 256;                                             \
        int r_ = idx >> 6, f_ = idx & 63;                                     \
        union { ushort u[4]; uint2 p; } pk_;                                  \
        pk_.u[0] = f2bf(xr[i_].x); pk_.u[1] = f2bf(xr[i_].y);                 \
        pk_.u[2] = f2bf(xr[i_].z); pk_.u[3] = f2bf(xr[i_].w);                 \
        *(uint2*)(lds + r_ * 512 + ((f_ * 8) ^ ((r_ & 7) << 4))) = pk_.p;     \
    } } while (0)

    LOADX(qb);                             // chunk 0 (q rows 0..63)

    for (int i = 0; i < NC; ++i) {
        __syncthreads();                   // xs free (and Ks/Vt free for i>2)
        STOREX();
        __syncthreads();                   // xs visible
        if (i + 1 < NC) {
            int r0 = (i + 1 < 2) ? (qb + (i + 1) * 64) : ((i - 1) * 64);
            LOADX(r0);                     // prefetch flies over compute
        }

        if (i < 2) {
            // ---- Q projection: waves 2i, 2i+1 own this chunk's 64 rows ----
            if ((wv >> 1) == i) {
                #pragma unroll
                for (int st = 0; st < 2; ++st) {
                    int rloc = (wv & 1) * 32 + st * 16;    // row base in chunk
                    float4v qacc[4];
                    #pragma unroll
                    for (int n = 0; n < 4; ++n) qacc[n] = (float4v){0.f,0.f,0.f,0.f};
                    #pragma unroll
                    for (int ks = 0; ks < 8; ++ks) {
                        short8v a = *(const short8v*)(lds + (rloc + lr) * 512 +
                                        ((ks * 64 + hi * 16) ^ bswz));
                        #pragma unroll
                        for (int n = 0; n < 4; ++n) {
                            short8v wf = *(const short8v*)(wcT +
                                (long)(n * 16 + lr) * Cn + ks * 32 + hi * 8);
                            qacc[n] = __builtin_amdgcn_mfma_f32_16x16x32_bf16(a, wf, qacc[n], 0, 0, 0);
                        }
                    }
                    // D [t][h] -> bounce scalar, then read back A-frags (intra-wave)
                    #pragma unroll
                    for (int n = 0; n < 4; ++n)
                        #pragma unroll
                        for (int reg = 0; reg < 4; ++reg) {
                            int t = hi * 4 + reg;
                            *(ushort*)(bnc + t * 128 + (((n * 16 + lr) * 2) ^ ((t & 7) << 4))) =
                                f2bf(qacc[n][reg]);
                        }
                    #pragma unroll
                    for (int ks = 0; ks < 2; ++ks)
                        qa[st][ks] = *(const short8v*)(bnc + lr * 128 +
                                        ((ks * 64 + hi * 16) ^ bswz));
                }
            }
        } else {
            const int kt = i - 2;
            // ---- K/V projection: wave wv does chunk rows [wv*16, wv*16+16) ----
            {
                const int rloc = wv * 16;
                float4v kacc[4], vacc[4];
                #pragma unroll
                for (int n = 0; n < 4; ++n) {
                    kacc[n] = (float4v){0.f, 0.f, 0.f, 0.f};
                    vacc[n] = kacc[n];
                }
                #pragma unroll
                for (int ks = 0; ks < 8; ++ks) {
                    short8v a = *(const short8v*)(lds + (rloc + lr) * 512 +
                                    ((ks * 64 + hi * 16) ^ bswz));
                    #pragma unroll
                    for (int n = 0; n < 4; ++n) {
                        short8v kf = *(const short8v*)(wcT +
                            (long)(64 + n * 16 + lr) * Cn + ks * 32 + hi * 8);
                        kacc[n] = __builtin_amdgcn_mfma_f32_16x16x32_bf16(a, kf, kacc[n], 0, 0, 0);
                        short8v vf = *(const short8v*)(wcT +
                            (long)(128 + n * 16 + lr) * Cn + ks * 32 + hi * 8);
                        vacc[n] = __builtin_amdgcn_mfma_f32_16x16x32_bf16(a, vf, vacc[n], 0, 0, 0);
                    }
                }
                // K: D col h=n*16+lr, rows t=rloc+hi*4+reg -> Ks[t][h] scalar
                #pragma unroll
                for (int n = 0; n < 4; ++n)
                    #pragma unroll
                    for (int reg = 0; reg < 4; ++reg) {
                        int t = rloc + hi * 4 + reg;
                        int h = n * 16 + lr;
                        *(ushort*)(lds + KOFF + t * 128 + ((h * 2) ^ ((t & 7) << 4))) =
                            f2bf(kacc[n][reg]);
                    }
                // V: 4 consecutive t at fixed h -> Vt[h][t0..t0+3] ushort4
                {
                    int t0 = rloc + hi * 4;
                    #pragma unroll
                    for (int n = 0; n < 4; ++n) {
                        int h = n * 16 + lr;
                        ushort4 pk;
                        pk.x = f2bf(vacc[n][0]); pk.y = f2bf(vacc[n][1]);
                        pk.z = f2bf(vacc[n][2]); pk.w = f2bf(vacc[n][3]);
                        *(ushort4*)(lds + VOFF + h * 128 + ((t0 * 2) ^ ((h & 7) << 4))) = pk;
                    }
                }
            }
            __syncthreads();               // Ks/Vt visible

            // ---- flash-attention update, per strip ----
            #pragma unroll
            for (int st = 0; st < 2; ++st) {
                const int qsg = qb + wv * 32 + st * 16;   // strip's first q row
                if (kt * 64 > qsg + 15) continue;         // fully masked
                const int mrow0 = qsg + hi * 4;

                float4v s4[4];
                #pragma unroll
                for (int n = 0; n < 4; ++n) s4[n] = (float4v){0.f, 0.f, 0.f, 0.f};
                #pragma unroll
                for (int ks = 0; ks < 2; ++ks) {
                    short8v a = qa[st][ks];
                    #pragma unroll
                    for (int n = 0; n < 4; ++n) {
                        int t = n * 16 + lr;
                        short8v bb = *(const short8v*)(lds + KOFF + t * 128 +
                                        ((ks * 64 + hi * 16) ^ ((t & 7) << 4)));
                        s4[n] = __builtin_amdgcn_mfma_f32_16x16x32_bf16(a, bb, s4[n], 0, 0, 0);
                    }
                }

                const bool partial = (kt * 64 + 63 > qsg);
                if (partial) {
                    #pragma unroll
                    for (int n = 0; n < 4; ++n) {
                        int kcol = kt * 64 + n * 16 + lr;
                        #pragma unroll
                        for (int reg = 0; reg < 4; ++reg) {
                            float y = s4[n][reg] * SCL;
                            s4[n][reg] = (kcol <= mrow0 + reg) ? y : -INFINITY;
                        }
                    }
                } else {
                    #pragma unroll
                    for (int n = 0; n < 4; ++n)
                        #pragma unroll
                        for (int reg = 0; reg < 4; ++reg) s4[n][reg] *= SCL;
                }

                #pragma unroll
                for (int reg = 0; reg < 4; ++reg) {
                    float mx = fmaxf(fmaxf(s4[0][reg], s4[1][reg]),
                                     fmaxf(s4[2][reg], s4[3][reg]));
                    mx = fmaxf(mx, __shfl_xor(mx, 1));
                    mx = fmaxf(mx, __shfl_xor(mx, 2));
                    mx = fmaxf(mx, __shfl_xor(mx, 4));
                    mx = fmaxf(mx, __shfl_xor(mx, 8));
                    float mN = fmaxf(m[st][reg], mx);
                    float sc = exp2f(m[st][reg] - mN);
                    float ps = 0.f;
                    #pragma unroll
                    for (int n = 0; n < 4; ++n) {
                        float p = exp2f(s4[n][reg] - mN);
                        s4[n][reg] = p;
                        ps += p;
                    }
                    ps += __shfl_xor(ps, 1);
                    ps += __shfl_xor(ps, 2);
                    ps += __shfl_xor(ps, 4);
                    ps += __shfl_xor(ps, 8);
                    l[st][reg] = l[st][reg] * sc + ps;
                    m[st][reg] = mN;
                    #pragma unroll
                    for (int n = 0; n < 4; ++n) o[st][n][reg] *= sc;
                }

                // P -> bounce (intra-wave), then PV
                #pragma unroll
                for (int n = 0; n < 4; ++n)
                    #pragma unroll
                    for (int reg = 0; reg < 4; ++reg) {
                        int t = hi * 4 + reg;
                        *(ushort*)(bnc + t * 128 + (((n * 16 + lr) * 2) ^ ((t & 7) << 4))) =
                            f2bf(s4[n][reg]);
                    }
                #pragma unroll
                for (int ks = 0; ks < 2; ++ks) {
                    short8v a = *(const short8v*)(bnc + lr * 128 +
                                    ((ks * 64 + hi * 16) ^ bswz));
                    #pragma unroll
                    for (int n = 0; n < 4; ++n) {
                        int h = n * 16 + lr;
                        short8v bb = *(const short8v*)(lds + VOFF + h * 128 +
                                        ((ks * 64 + hi * 16) ^ ((h & 7) << 4)));
                        o[st][n] = __builtin_amdgcn_mfma_f32_16x16x32_bf16(a, bb, o[st][n], 0, 0, 0);
                    }
                }
            }
        }
    }

    // ---- epilogue ----
    #pragma unroll
    for (int st = 0; st < 2; ++st) {
        #pragma unroll
        for (int reg = 0; reg < 4; ++reg) {
            float inv = 1.0f / l[st][reg];
            int qrow = qb + wv * 32 + st * 16 + hi * 4 + reg;
            float* orow = out + obase + (long)qrow * Hn;
            #pragma unroll
            for (int n = 0; n < 4; ++n)
                orow[n * 16 + lr] = o[st][n][reg] * inv;
        }
    }
#undef LOADX
#undef STOREX
}

extern "C" void kernel_launch(void* const* d_in, const int* in_sizes, int n_in,
                              void* d_out, int out_size, void* d_ws, size_t ws_size,
                              hipStream_t stream) {
    const float* x  = (const float*)d_in[0];
    const float* Wq = (const float*)d_in[1];
    const float* Wk = (const float*)d_in[2];
    const float* Wv = (const float*)d_in[3];
    float* out = (float*)d_out;

    ushort* wcT = (ushort*)d_ws;     // 96 KB

    prep_w_kernel<<<dim3(192), 256, 0, stream>>>(Wq, Wk, Wv, wcT);
    fused_attn_kernel<<<dim3(4, Bn), 256, 0, stream>>>(x, wcT, out);
}

// Round 19
// 48.833 us; speedup vs baseline: 5.5447x; 5.5447x over previous
//
#include <hip/hip_runtime.h>
#include <hip/hip_bf16.h>
#include <math.h>

#define Bn 128
#define Tn 512
#define Cn 256
#define Hn 64
#define HP2 72          // padded bf16 LDS stride for attn tiles (144 B)
#define SCL 0.18033688011112042f   // log2(e)/8 : exp2-domain softmax scale

typedef __attribute__((ext_vector_type(8))) short short8v;   // 8 bf16
typedef __attribute__((ext_vector_type(4))) float float4v;   // MFMA C/D

__device__ __forceinline__ ushort f2bf(float f) {
    __hip_bfloat16 h = __float2bfloat16(f);   // RNE
    return *reinterpret_cast<ushort*>(&h);
}

// ---------------------------------------------------------------------------
// Prep: wcT3 = W as 4 contiguous K-chunks of [192 out-cols][64 k] bf16,
// pre-swizzled (k2 ^ ((row&7)<<3) in ushorts == byte ^ ((row&7)<<4)) so a
// LINEAR global_load_lds of a 24 KB chunk lands XOR-swizzled in LDS.
// Row order = output col: 0-63 q, 64-127 k, 128-191 v.
// ---------------------------------------------------------------------------
__global__ __launch_bounds__(256) void prep_w_kernel(
    const float* __restrict__ Wq, const float* __restrict__ Wk,
    const float* __restrict__ Wv, ushort* __restrict__ wcT3)
{
    const int row = blockIdx.x;          // 0..191 : output col
    const int c   = threadIdx.x;         // 0..255 : k
    const int kc  = c >> 6;
    const int k2  = c & 63;
    const float* W = (row < 64) ? Wq : (row < 128) ? Wk : Wv;
    const int h = row & 63;
    wcT3[(kc * 192 + row) * 64 + (k2 ^ ((row & 7) << 3))] = f2bf(W[c * Hn + h]);
}

// ---------------------------------------------------------------------------
// QKV GEMM v10 (m97-shaped): 512 blocks x 256 thr (4 waves), block tile
// 128 rows x 192 cols (FULL N -> x read once), K chunked BK=64, LDS
// double-buffered 2x(16K x + 24K W) = 80 KB -> 2 blocks/CU.
// Wave grid 2x2: wave-tile 64 rows x 96 cols (R=4 strips, F=6 frags):
// per ks 10 ds_read_b128 feed 24 MFMAs. Pipeline: per chunk {barrier; issue
// W-DMA + x loads for c+1; MFMA on c; cvt+ds_write c+1}. Epilogue: q/k/v
// bounced via freed LDS buffers -> 12 coalesced uint4 stores/thread.
// Best measured configuration of the session (r15: 48.7 µs total).
// ---------------------------------------------------------------------------
__global__ __launch_bounds__(256) void qkv_mfma_kernel(
    const float* __restrict__ x, const ushort* __restrict__ wcT3,
    ushort* __restrict__ q, ushort* __restrict__ k, ushort* __restrict__ vT)
{
    __shared__ char lds[81920];
    // xbuf0 @ 0, xbuf1 @ 16384 (each [128 r][64 k] bf16, 128 B rows, swz)
    // wbuf0 @ 32768, wbuf1 @ 57344 (each [192 r][64 k] bf16, swz)
    // epilogue overlay: q-bounce @ 0 (16K), k-bounce @ 16384 (16K),
    //                   v-bounce @ 32768 (16K, [64 h][128 t])

    const int tid  = threadIdx.x;
    const int lane = tid & 63;
    const int wv   = tid >> 6;             // 0..3
    const int lr   = lane & 15;
    const int hi   = lane >> 4;
    const int wr   = wv >> 1;              // 0..1 : 64-row group
    const int wc   = wv & 1;               // 0..1 : 96-col group
    const long rows0 = (long)blockIdx.x * 128;

    // ---- prologue: W chunk0 DMA + x chunk0 ----
    {
        const char* gw = (const char*)wcT3;
        #pragma unroll
        for (int i = 0; i < 6; ++i) {
            int off = (wv * 6 + i) * 1024;
            __builtin_amdgcn_global_load_lds(
                (const __attribute__((address_space(1))) unsigned int*)(gw + off + (lane << 4)),
                (__attribute__((address_space(3))) unsigned int*)(lds + 32768 + off),
                16, 0, 0);
        }
    }
    {
        const float4* x4 = (const float4*)x;
        float4 xr[8];
        #pragma unroll
        for (int i = 0; i < 8; ++i) {
            int idx = tid + i * 256;                 // 0..2047
            int r   = idx >> 4;
            int f   = idx & 15;
            xr[i] = x4[(rows0 + r) * 64 + f];        // chunk 0: f4 0..15
        }
        #pragma unroll
        for (int i = 0; i < 8; ++i) {
            int idx = tid + i * 256;
            int r   = idx >> 4;
            int f   = idx & 15;
            union { ushort u[4]; uint2 p; } pk;
            pk.u[0] = f2bf(xr[i].x); pk.u[1] = f2bf(xr[i].y);
            pk.u[2] = f2bf(xr[i].z); pk.u[3] = f2bf(xr[i].w);
            *(uint2*)(lds + r * 128 + ((f * 8) ^ ((r & 7) << 4))) = pk.p;
        }
    }

    float4v acc[4][6];
    #pragma unroll
    for (int s = 0; s < 4; ++s)
        #pragma unroll
        for (int n = 0; n < 6; ++n) acc[s][n] = (float4v){0.f, 0.f, 0.f, 0.f};

    for (int c = 0; c < 4; ++c) {
        __syncthreads();     // buf[c&1] staged (DMA drained by barrier's vmcnt)

        const int par = c & 1;
        float4 xn[8];
        if (c < 3) {
            // issue next W chunk DMA -> wbuf[!par]
            const char* gw = (const char*)wcT3 + (long)(c + 1) * 24576;
            #pragma unroll
            for (int i = 0; i < 6; ++i) {
                int off = (wv * 6 + i) * 1024;
                __builtin_amdgcn_global_load_lds(
                    (const __attribute__((address_space(1))) unsigned int*)(gw + off + (lane << 4)),
                    (__attribute__((address_space(3))) unsigned int*)(lds + 32768 + (1 - par) * 24576 + off),
                    16, 0, 0);
            }
            // issue next x loads
            const float4* x4 = (const float4*)x;
            #pragma unroll
            for (int i = 0; i < 8; ++i) {
                int idx = tid + i * 256;
                int r   = idx >> 4;
                int f   = idx & 15;
                xn[i] = x4[(rows0 + r) * 64 + (c + 1) * 16 + f];
            }
        }

        // ---- MFMA on chunk c ----
        const char* xb = lds + par * 16384;
        const char* wb = lds + 32768 + par * 24576;
        #pragma unroll
        for (int ks = 0; ks < 2; ++ks) {
            const int kb = ks * 64 + hi * 16;
            short8v a[4];
            #pragma unroll
            for (int s = 0; s < 4; ++s) {
                int r = wr * 64 + s * 16 + lr;
                a[s] = *(const short8v*)(xb + r * 128 + (kb ^ ((r & 7) << 4)));
            }
            #pragma unroll
            for (int n = 0; n < 6; ++n) {
                int wrow = wc * 96 + n * 16 + lr;
                short8v wf = *(const short8v*)(wb + wrow * 128 + (kb ^ ((wrow & 7) << 4)));
                #pragma unroll
                for (int s = 0; s < 4; ++s)
                    acc[s][n] = __builtin_amdgcn_mfma_f32_16x16x32_bf16(a[s], wf, acc[s][n], 0, 0, 0);
            }
        }

        // ---- cvt + ds_write next x chunk -> xbuf[!par] ----
        if (c < 3) {
            char* xd = lds + (1 - par) * 16384;
            #pragma unroll
            for (int i = 0; i < 8; ++i) {
                int idx = tid + i * 256;
                int r   = idx >> 4;
                int f   = idx & 15;
                union { ushort u[4]; uint2 p; } pk;
                pk.u[0] = f2bf(xn[i].x); pk.u[1] = f2bf(xn[i].y);
                pk.u[2] = f2bf(xn[i].z); pk.u[3] = f2bf(xn[i].w);
                *(uint2*)(xd + r * 128 + ((f * 8) ^ ((r & 7) << 4))) = pk.p;
            }
        }
    }

    __syncthreads();   // all MFMA reads done -> overlay buffers as bounce

    // ---- bounce writes: D lane (lr,hi) holds h = col16+lr, t = tb+reg ----
    #pragma unroll
    for (int s = 0; s < 4; ++s) {
        const int tb = wr * 64 + s * 16 + hi * 4;      // local t (+reg)
        #pragma unroll
        for (int n = 0; n < 6; ++n) {
            const int col16 = wc * 96 + n * 16;        // wave-uniform
            if (col16 < 128) {                         // q or k: [t][h] 2B
                char* qkb = lds + ((col16 < 64) ? 0 : 16384);
                int h = (col16 + lr) & 63;
                #pragma unroll
                for (int reg = 0; reg < 4; ++reg) {
                    int t = tb + reg;
                    *(ushort*)(qkb + t * 128 + ((h * 2) ^ ((t & 7) << 4))) =
                        f2bf(acc[s][n][reg]);
                }
            } else {                                   // v: [h][t] ushort4
                int h = col16 - 128 + lr;
                ushort4 pk;
                pk.x = f2bf(acc[s][n][0]); pk.y = f2bf(acc[s][n][1]);
                pk.z = f2bf(acc[s][n][2]); pk.w = f2bf(acc[s][n][3]);
                *(ushort4*)(lds + 32768 + h * 256 + ((tb * 2) ^ ((h & 7) << 4))) = pk;
            }
        }
    }
    __syncthreads();

    // ---- coalesced stores: 4 uint4/thread each for q, k, vT ----
    {
        const int bb = (int)(rows0 >> 9);
        const int t0 = (int)(rows0 & 511);
        #pragma unroll
        for (int i = 0; i < 4; ++i) {
            int idx = tid + i * 256;                   // 0..1023
            int t   = idx >> 3;
            int f   = idx & 7;
            uint4 vq = *(const uint4*)(lds + t * 128 + ((f * 16) ^ ((t & 7) << 4)));
            *(uint4*)(q + (rows0 + t) * Hn + f * 8) = vq;
            uint4 vk = *(const uint4*)(lds + 16384 + t * 128 + ((f * 16) ^ ((t & 7) << 4)));
            *(uint4*)(k + (rows0 + t) * Hn + f * 8) = vk;
            int h  = idx >> 4;
            int fv = idx & 15;
            uint4 vv = *(const uint4*)(lds + 32768 + h * 256 + ((fv * 16) ^ ((h & 7) << 4)));
            *(uint4*)(vT + ((long)bb * Hn + h) * Tn + t0 + fv * 8) = vv;
        }
    }
}

// ---------------------------------------------------------------------------
// MFMA flash attention, 128-row Q tile, 8 waves (512 thr).
// Work-balanced 1D grid: each CU's 2 resident blocks share batch b and sum
// to 10 K-tiles. Q fragments in registers; K/Vt single-buffered LDS with
// reg-staged prefetch. Softmax in exp2 domain. ~13 µs measured.
// ---------------------------------------------------------------------------
__global__ __launch_bounds__(512) void attn_mfma_kernel(
    const ushort* __restrict__ q, const ushort* __restrict__ k,
    const ushort* __restrict__ vT, float* __restrict__ out)
{
    __shared__ ushort Ks[64 * HP2];        // [key s][h]
    __shared__ ushort Vt[64 * HP2];        // [h][key s]
    __shared__ ushort Pl[8][16 * HP2];     // per-wave P rows

    const int tid = threadIdx.x;
    const int f   = blockIdx.x;            // 0..511
    const int c   = f & 255;
    const int b   = c >> 1;
    const int par = c & 1;
    const int qtp = (f < 256) ? par : (3 - par);   // q-tile 0..3
    const int ntiles = 2 * qtp + 2;

    const long base  = (long)b * Tn * Hn;
    const int lane = tid & 63;
    const int wv   = tid >> 6;             // 0..7
    const int lr   = lane & 15;
    const int hi   = lane >> 4;

    const int qrow_g = qtp * 128 + wv * 16;
    const int mrow0  = qrow_g + hi * 4;

    short8v qa[2];
    {
        const ushort* qp = q + base + (long)(qrow_g + lr) * Hn + hi * 8;
        qa[0] = *(const short8v*)(qp);
        qa[1] = *(const short8v*)(qp + 32);
    }

    const int sr  = tid >> 3;
    const int sc8 = tid & 7;
    uint4 kreg = *(const uint4*)(k + base + (long)sr * Hn + sc8 * 8);
    uint4 vreg = *(const uint4*)(vT + base + (long)sr * Tn + sc8 * 8);

    float4v o[4];
    #pragma unroll
    for (int n = 0; n < 4; ++n) o[n] = (float4v){0.f, 0.f, 0.f, 0.f};
    float m[4], l[4];
    #pragma unroll
    for (int reg = 0; reg < 4; ++reg) { m[reg] = -INFINITY; l[reg] = 0.f; }

    for (int kt = 0; kt < ntiles; ++kt) {
        __syncthreads();
        *(uint4*)&Ks[sr * HP2 + sc8 * 8] = kreg;
        *(uint4*)&Vt[sr * HP2 + sc8 * 8] = vreg;
        __syncthreads();
        if (kt + 1 < ntiles) {
            kreg = *(const uint4*)(k  + base + (long)((kt + 1) * 64 + sr) * Hn + sc8 * 8);
            vreg = *(const uint4*)(vT + base + (long)sr * Tn + (kt + 1) * 64 + sc8 * 8);
        }
        if (kt * 64 > qrow_g + 15) continue;

        float4v s4[4];
        #pragma unroll
        for (int n = 0; n < 4; ++n) s4[n] = (float4v){0.f, 0.f, 0.f, 0.f};
        #pragma unroll
        for (int ks = 0; ks < 2; ++ks) {
            short8v a = qa[ks];
            #pragma unroll
            for (int n = 0; n < 4; ++n) {
                short8v bb = *(const short8v*)&Ks[(n * 16 + lr) * HP2 + ks * 32 + hi * 8];
                s4[n] = __builtin_amdgcn_mfma_f32_16x16x32_bf16(a, bb, s4[n], 0, 0, 0);
            }
        }

        const bool partial = (kt * 64 + 63 > qrow_g);
        if (partial) {
            #pragma unroll
            for (int n = 0; n < 4; ++n) {
                int kcol = kt * 64 + n * 16 + lr;
                #pragma unroll
                for (int reg = 0; reg < 4; ++reg) {
                    float y = s4[n][reg] * SCL;
                    s4[n][reg] = (kcol <= mrow0 + reg) ? y : -INFINITY;
                }
            }
        } else {
            #pragma unroll
            for (int n = 0; n < 4; ++n)
                #pragma unroll
                for (int reg = 0; reg < 4; ++reg) s4[n][reg] *= SCL;
        }

        #pragma unroll
        for (int reg = 0; reg < 4; ++reg) {
            float mx = fmaxf(fmaxf(s4[0][reg], s4[1][reg]),
                             fmaxf(s4[2][reg], s4[3][reg]));
            mx = fmaxf(mx, __shfl_xor(mx, 1));
            mx = fmaxf(mx, __shfl_xor(mx, 2));
            mx = fmaxf(mx, __shfl_xor(mx, 4));
            mx = fmaxf(mx, __shfl_xor(mx, 8));
            float mN = fmaxf(m[reg], mx);
            float sc = exp2f(m[reg] - mN);
            float ps = 0.f;
            #pragma unroll
            for (int n = 0; n < 4; ++n) {
                float p = exp2f(s4[n][reg] - mN);
                s4[n][reg] = p;
                ps += p;
            }
            ps += __shfl_xor(ps, 1);
            ps += __shfl_xor(ps, 2);
            ps += __shfl_xor(ps, 4);
            ps += __shfl_xor(ps, 8);
            l[reg] = l[reg] * sc + ps;
            m[reg] = mN;
            #pragma unroll
            for (int n = 0; n < 4; ++n) o[n][reg] *= sc;
        }

        #pragma unroll
        for (int n = 0; n < 4; ++n)
            #pragma unroll
            for (int reg = 0; reg < 4; ++reg)
                Pl[wv][(hi * 4 + reg) * HP2 + n * 16 + lr] = f2bf(s4[n][reg]);

        #pragma unroll
        for (int ks = 0; ks < 2; ++ks) {
            short8v a = *(const short8v*)&Pl[wv][lr * HP2 + ks * 32 + hi * 8];
            #pragma unroll
            for (int n = 0; n < 4; ++n) {
                short8v bb = *(const short8v*)&Vt[(n * 16 + lr) * HP2 + ks * 32 + hi * 8];
                o[n] = __builtin_amdgcn_mfma_f32_16x16x32_bf16(a, bb, o[n], 0, 0, 0);
            }
        }
    }

    #pragma unroll
    for (int reg = 0; reg < 4; ++reg) {
        float inv = 1.0f / l[reg];
        float* orow = out + base + (long)(mrow0 + reg) * Hn;
        #pragma unroll
        for (int n = 0; n < 4; ++n)
            orow[n * 16 + lr] = o[n][reg] * inv;
    }
}

extern "C" void kernel_launch(void* const* d_in, const int* in_sizes, int n_in,
                              void* d_out, int out_size, void* d_ws, size_t ws_size,
                              hipStream_t stream) {
    const float* x  = (const float*)d_in[0];
    const float* Wq = (const float*)d_in[1];
    const float* Wk = (const float*)d_in[2];
    const float* Wv = (const float*)d_in[3];
    float* out = (float*)d_out;

    const size_t n = (size_t)Bn * Tn * Hn;
    ushort* qws  = (ushort*)d_ws;
    ushort* kws  = qws + n;
    ushort* vTs  = kws + n;
    ushort* wcT3 = vTs + n;      // K-chunked pre-swizzled bf16 W, 96 KB

    prep_w_kernel<<<dim3(192), 256, 0, stream>>>(Wq, Wk, Wv, wcT3);
    qkv_mfma_kernel<<<dim3(512), 256, 0, stream>>>(x, wcT3, qws, kws, vTs);
    attn_mfma_kernel<<<dim3(512), 512, 0, stream>>>(qws, kws, vTs, out);
}

// Round 20
// 48.676 us; speedup vs baseline: 5.5625x; 1.0032x over previous
//
#include <hip/hip_runtime.h>
#include <hip/hip_bf16.h>
#include <math.h>

#define Bn 128
#define Tn 512
#define Cn 256
#define Hn 64
#define HP2 72          // padded bf16 LDS stride for attn tiles (144 B)
#define SCL 0.18033688011112042f   // log2(e)/8 : exp2-domain softmax scale

typedef __attribute__((ext_vector_type(8))) short short8v;   // 8 bf16
typedef __attribute__((ext_vector_type(4))) float float4v;   // MFMA C/D

__device__ __forceinline__ ushort f2bf(float f) {
    __hip_bfloat16 h = __float2bfloat16(f);   // RNE
    return *reinterpret_cast<ushort*>(&h);
}

// ---------------------------------------------------------------------------
// Prep: wcT3 = W as 4 contiguous K-chunks of [192 out-cols][64 k] bf16,
// pre-swizzled (k2 ^ ((row&7)<<3)) so a LINEAR global_load_lds of a 24 KB
// chunk lands XOR-swizzled in LDS. Row order: 0-63 q, 64-127 k, 128-191 v.
// ---------------------------------------------------------------------------
__global__ __launch_bounds__(256) void prep_w_kernel(
    const float* __restrict__ Wq, const float* __restrict__ Wk,
    const float* __restrict__ Wv, ushort* __restrict__ wcT3)
{
    const int row = blockIdx.x;          // 0..191 : output col
    const int c   = threadIdx.x;         // 0..255 : k
    const int kc  = c >> 6;
    const int k2  = c & 63;
    const float* W = (row < 64) ? Wq : (row < 128) ? Wk : Wv;
    const int h = row & 63;
    wcT3[(kc * 192 + row) * 64 + (k2 ^ ((row & 7) << 3))] = f2bf(W[c * Hn + h]);
}

// ---------------------------------------------------------------------------
// QKV GEMM v10 + T5 setprio around the MFMA cluster. 512 blocks x 256 thr,
// 128x192 tile, BK=64 double-buffered (80 KB -> 2 blocks/CU). r15 structure
// (best measured: 48.7 µs total), MFMA cluster now priority-boosted.
// ---------------------------------------------------------------------------
__global__ __launch_bounds__(256) void qkv_mfma_kernel(
    const float* __restrict__ x, const ushort* __restrict__ wcT3,
    ushort* __restrict__ q, ushort* __restrict__ k, ushort* __restrict__ vT)
{
    __shared__ char lds[81920];
    // xbuf0 @ 0, xbuf1 @ 16384; wbuf0 @ 32768, wbuf1 @ 57344
    // epilogue overlay: q @0, k @16384, v @32768

    const int tid  = threadIdx.x;
    const int lane = tid & 63;
    const int wv   = tid >> 6;             // 0..3
    const int lr   = lane & 15;
    const int hi   = lane >> 4;
    const int wr   = wv >> 1;              // 0..1 : 64-row group
    const int wc   = wv & 1;               // 0..1 : 96-col group
    const long rows0 = (long)blockIdx.x * 128;

    // ---- prologue: W chunk0 DMA + x chunk0 ----
    {
        const char* gw = (const char*)wcT3;
        #pragma unroll
        for (int i = 0; i < 6; ++i) {
            int off = (wv * 6 + i) * 1024;
            __builtin_amdgcn_global_load_lds(
                (const __attribute__((address_space(1))) unsigned int*)(gw + off + (lane << 4)),
                (__attribute__((address_space(3))) unsigned int*)(lds + 32768 + off),
                16, 0, 0);
        }
    }
    {
        const float4* x4 = (const float4*)x;
        float4 xr[8];
        #pragma unroll
        for (int i = 0; i < 8; ++i) {
            int idx = tid + i * 256;
            int r   = idx >> 4;
            int f   = idx & 15;
            xr[i] = x4[(rows0 + r) * 64 + f];
        }
        #pragma unroll
        for (int i = 0; i < 8; ++i) {
            int idx = tid + i * 256;
            int r   = idx >> 4;
            int f   = idx & 15;
            union { ushort u[4]; uint2 p; } pk;
            pk.u[0] = f2bf(xr[i].x); pk.u[1] = f2bf(xr[i].y);
            pk.u[2] = f2bf(xr[i].z); pk.u[3] = f2bf(xr[i].w);
            *(uint2*)(lds + r * 128 + ((f * 8) ^ ((r & 7) << 4))) = pk.p;
        }
    }

    float4v acc[4][6];
    #pragma unroll
    for (int s = 0; s < 4; ++s)
        #pragma unroll
        for (int n = 0; n < 6; ++n) acc[s][n] = (float4v){0.f, 0.f, 0.f, 0.f};

    for (int c = 0; c < 4; ++c) {
        __syncthreads();     // buf[c&1] staged

        const int par = c & 1;
        float4 xn[8];
        if (c < 3) {
            const char* gw = (const char*)wcT3 + (long)(c + 1) * 24576;
            #pragma unroll
            for (int i = 0; i < 6; ++i) {
                int off = (wv * 6 + i) * 1024;
                __builtin_amdgcn_global_load_lds(
                    (const __attribute__((address_space(1))) unsigned int*)(gw + off + (lane << 4)),
                    (__attribute__((address_space(3))) unsigned int*)(lds + 32768 + (1 - par) * 24576 + off),
                    16, 0, 0);
            }
            const float4* x4 = (const float4*)x;
            #pragma unroll
            for (int i = 0; i < 8; ++i) {
                int idx = tid + i * 256;
                int r   = idx >> 4;
                int f   = idx & 15;
                xn[i] = x4[(rows0 + r) * 64 + (c + 1) * 16 + f];
            }
        }

        // ---- MFMA on chunk c (priority-boosted) ----
        const char* xb = lds + par * 16384;
        const char* wb = lds + 32768 + par * 24576;
        __builtin_amdgcn_s_setprio(1);
        #pragma unroll
        for (int ks = 0; ks < 2; ++ks) {
            const int kb = ks * 64 + hi * 16;
            short8v a[4];
            #pragma unroll
            for (int s = 0; s < 4; ++s) {
                int r = wr * 64 + s * 16 + lr;
                a[s] = *(const short8v*)(xb + r * 128 + (kb ^ ((r & 7) << 4)));
            }
            #pragma unroll
            for (int n = 0; n < 6; ++n) {
                int wrow = wc * 96 + n * 16 + lr;
                short8v wf = *(const short8v*)(wb + wrow * 128 + (kb ^ ((wrow & 7) << 4)));
                #pragma unroll
                for (int s = 0; s < 4; ++s)
                    acc[s][n] = __builtin_amdgcn_mfma_f32_16x16x32_bf16(a[s], wf, acc[s][n], 0, 0, 0);
            }
        }
        __builtin_amdgcn_s_setprio(0);

        // ---- cvt + ds_write next x chunk ----
        if (c < 3) {
            char* xd = lds + (1 - par) * 16384;
            #pragma unroll
            for (int i = 0; i < 8; ++i) {
                int idx = tid + i * 256;
                int r   = idx >> 4;
                int f   = idx & 15;
                union { ushort u[4]; uint2 p; } pk;
                pk.u[0] = f2bf(xn[i].x); pk.u[1] = f2bf(xn[i].y);
                pk.u[2] = f2bf(xn[i].z); pk.u[3] = f2bf(xn[i].w);
                *(uint2*)(xd + r * 128 + ((f * 8) ^ ((r & 7) << 4))) = pk.p;
            }
        }
    }

    __syncthreads();   // all MFMA reads done -> overlay buffers as bounce

    #pragma unroll
    for (int s = 0; s < 4; ++s) {
        const int tb = wr * 64 + s * 16 + hi * 4;
        #pragma unroll
        for (int n = 0; n < 6; ++n) {
            const int col16 = wc * 96 + n * 16;
            if (col16 < 128) {
                char* qkb = lds + ((col16 < 64) ? 0 : 16384);
                int h = (col16 + lr) & 63;
                #pragma unroll
                for (int reg = 0; reg < 4; ++reg) {
                    int t = tb + reg;
                    *(ushort*)(qkb + t * 128 + ((h * 2) ^ ((t & 7) << 4))) =
                        f2bf(acc[s][n][reg]);
                }
            } else {
                int h = col16 - 128 + lr;
                ushort4 pk;
                pk.x = f2bf(acc[s][n][0]); pk.y = f2bf(acc[s][n][1]);
                pk.z = f2bf(acc[s][n][2]); pk.w = f2bf(acc[s][n][3]);
                *(ushort4*)(lds + 32768 + h * 256 + ((tb * 2) ^ ((h & 7) << 4))) = pk;
            }
        }
    }
    __syncthreads();

    {
        const int bb = (int)(rows0 >> 9);
        const int t0 = (int)(rows0 & 511);
        #pragma unroll
        for (int i = 0; i < 4; ++i) {
            int idx = tid + i * 256;
            int t   = idx >> 3;
            int f   = idx & 7;
            uint4 vq = *(const uint4*)(lds + t * 128 + ((f * 16) ^ ((t & 7) << 4)));
            *(uint4*)(q + (rows0 + t) * Hn + f * 8) = vq;
            uint4 vk = *(const uint4*)(lds + 16384 + t * 128 + ((f * 16) ^ ((t & 7) << 4)));
            *(uint4*)(k + (rows0 + t) * Hn + f * 8) = vk;
            int h  = idx >> 4;
            int fv = idx & 15;
            uint4 vv = *(const uint4*)(lds + 32768 + h * 256 + ((fv * 16) ^ ((h & 7) << 4)));
            *(uint4*)(vT + ((long)bb * Hn + h) * Tn + t0 + fv * 8) = vv;
        }
    }
}

// ---------------------------------------------------------------------------
// MFMA flash attention + T5 setprio around MFMA clusters (m191: +4-7% on
// attn). Structure unchanged from r15/r19 (~13 µs measured).
// ---------------------------------------------------------------------------
__global__ __launch_bounds__(512) void attn_mfma_kernel(
    const ushort* __restrict__ q, const ushort* __restrict__ k,
    const ushort* __restrict__ vT, float* __restrict__ out)
{
    __shared__ ushort Ks[64 * HP2];        // [key s][h]
    __shared__ ushort Vt[64 * HP2];        // [h][key s]
    __shared__ ushort Pl[8][16 * HP2];     // per-wave P rows

    const int tid = threadIdx.x;
    const int f   = blockIdx.x;            // 0..511
    const int c   = f & 255;
    const int b   = c >> 1;
    const int par = c & 1;
    const int qtp = (f < 256) ? par : (3 - par);   // q-tile 0..3
    const int ntiles = 2 * qtp + 2;

    const long base  = (long)b * Tn * Hn;
    const int lane = tid & 63;
    const int wv   = tid >> 6;             // 0..7
    const int lr   = lane & 15;
    const int hi   = lane >> 4;

    const int qrow_g = qtp * 128 + wv * 16;
    const int mrow0  = qrow_g + hi * 4;

    short8v qa[2];
    {
        const ushort* qp = q + base + (long)(qrow_g + lr) * Hn + hi * 8;
        qa[0] = *(const short8v*)(qp);
        qa[1] = *(const short8v*)(qp + 32);
    }

    const int sr  = tid >> 3;
    const int sc8 = tid & 7;
    uint4 kreg = *(const uint4*)(k + base + (long)sr * Hn + sc8 * 8);
    uint4 vreg = *(const uint4*)(vT + base + (long)sr * Tn + sc8 * 8);

    float4v o[4];
    #pragma unroll
    for (int n = 0; n < 4; ++n) o[n] = (float4v){0.f, 0.f, 0.f, 0.f};
    float m[4], l[4];
    #pragma unroll
    for (int reg = 0; reg < 4; ++reg) { m[reg] = -INFINITY; l[reg] = 0.f; }

    for (int kt = 0; kt < ntiles; ++kt) {
        __syncthreads();
        *(uint4*)&Ks[sr * HP2 + sc8 * 8] = kreg;
        *(uint4*)&Vt[sr * HP2 + sc8 * 8] = vreg;
        __syncthreads();
        if (kt + 1 < ntiles) {
            kreg = *(const uint4*)(k  + base + (long)((kt + 1) * 64 + sr) * Hn + sc8 * 8);
            vreg = *(const uint4*)(vT + base + (long)sr * Tn + (kt + 1) * 64 + sc8 * 8);
        }
        if (kt * 64 > qrow_g + 15) continue;

        float4v s4[4];
        #pragma unroll
        for (int n = 0; n < 4; ++n) s4[n] = (float4v){0.f, 0.f, 0.f, 0.f};
        __builtin_amdgcn_s_setprio(1);
        #pragma unroll
        for (int ks = 0; ks < 2; ++ks) {
            short8v a = qa[ks];
            #pragma unroll
            for (int n = 0; n < 4; ++n) {
                short8v bb = *(const short8v*)&Ks[(n * 16 + lr) * HP2 + ks * 32 + hi * 8];
                s4[n] = __builtin_amdgcn_mfma_f32_16x16x32_bf16(a, bb, s4[n], 0, 0, 0);
            }
        }
        __builtin_amdgcn_s_setprio(0);

        const bool partial = (kt * 64 + 63 > qrow_g);
        if (partial) {
            #pragma unroll
            for (int n = 0; n < 4; ++n) {
                int kcol = kt * 64 + n * 16 + lr;
                #pragma unroll
                for (int reg = 0; reg < 4; ++reg) {
                    float y = s4[n][reg] * SCL;
                    s4[n][reg] = (kcol <= mrow0 + reg) ? y : -INFINITY;
                }
            }
        } else {
            #pragma unroll
            for (int n = 0; n < 4; ++n)
                #pragma unroll
                for (int reg = 0; reg < 4; ++reg) s4[n][reg] *= SCL;
        }

        #pragma unroll
        for (int reg = 0; reg < 4; ++reg) {
            float mx = fmaxf(fmaxf(s4[0][reg], s4[1][reg]),
                             fmaxf(s4[2][reg], s4[3][reg]));
            mx = fmaxf(mx, __shfl_xor(mx, 1));
            mx = fmaxf(mx, __shfl_xor(mx, 2));
            mx = fmaxf(mx, __shfl_xor(mx, 4));
            mx = fmaxf(mx, __shfl_xor(mx, 8));
            float mN = fmaxf(m[reg], mx);
            float sc = exp2f(m[reg] - mN);
            float ps = 0.f;
            #pragma unroll
            for (int n = 0; n < 4; ++n) {
                float p = exp2f(s4[n][reg] - mN);
                s4[n][reg] = p;
                ps += p;
            }
            ps += __shfl_xor(ps, 1);
            ps += __shfl_xor(ps, 2);
            ps += __shfl_xor(ps, 4);
            ps += __shfl_xor(ps, 8);
            l[reg] = l[reg] * sc + ps;
            m[reg] = mN;
            #pragma unroll
            for (int n = 0; n < 4; ++n) o[n][reg] *= sc;
        }

        #pragma unroll
        for (int n = 0; n < 4; ++n)
            #pragma unroll
            for (int reg = 0; reg < 4; ++reg)
                Pl[wv][(hi * 4 + reg) * HP2 + n * 16 + lr] = f2bf(s4[n][reg]);

        __builtin_amdgcn_s_setprio(1);
        #pragma unroll
        for (int ks = 0; ks < 2; ++ks) {
            short8v a = *(const short8v*)&Pl[wv][lr * HP2 + ks * 32 + hi * 8];
            #pragma unroll
            for (int n = 0; n < 4; ++n) {
                short8v bb = *(const short8v*)&Vt[(n * 16 + lr) * HP2 + ks * 32 + hi * 8];
                o[n] = __builtin_amdgcn_mfma_f32_16x16x32_bf16(a, bb, o[n], 0, 0, 0);
            }
        }
        __builtin_amdgcn_s_setprio(0);
    }

    #pragma unroll
    for (int reg = 0; reg < 4; ++reg) {
        float inv = 1.0f / l[reg];
        float* orow = out + base + (long)(mrow0 + reg) * Hn;
        #pragma unroll
        for (int n = 0; n < 4; ++n)
            orow[n * 16 + lr] = o[n][reg] * inv;
    }
}

extern "C" void kernel_launch(void* const* d_in, const int* in_sizes, int n_in,
                              void* d_out, int out_size, void* d_ws, size_t ws_size,
                              hipStream_t stream) {
    const float* x  = (const float*)d_in[0];
    const float* Wq = (const float*)d_in[1];
    const float* Wk = (const float*)d_in[2];
    const float* Wv = (const float*)d_in[3];
    float* out = (float*)d_out;

    const size_t n = (size_t)Bn * Tn * Hn;
    ushort* qws  = (ushort*)d_ws;
    ushort* kws  = qws + n;
    ushort* vTs  = kws + n;
    ushort* wcT3 = vTs + n;      // K-chunked pre-swizzled bf16 W, 96 KB

    prep_w_kernel<<<dim3(192), 256, 0, stream>>>(Wq, Wk, Wv, wcT3);
    qkv_mfma_kernel<<<dim3(512), 256, 0, stream>>>(x, wcT3, qws, kws, vTs);
    attn_mfma_kernel<<<dim3(512), 512, 0, stream>>>(qws, kws, vTs, out);
}